// Round 1
// baseline (1355.018 us; speedup 1.0000x reference)
//
#include <hip/hip_runtime.h>
#include <math.h>

#define B_ 128
#define L_ 512
#define D_ 512
#define E_ 64
#define H_ 512
#define V_ 17

// ---------------- DH precompute: DH[v][h] = sum_e W1[h][D+e] * table[v][e], row 0 zeroed
__global__ void dh_kernel(const float* __restrict__ W1, const float* __restrict__ table,
                          float* __restrict__ DH) {
  int h = threadIdx.x; // 512 threads
  float w[E_];
#pragma unroll
  for (int e = 0; e < E_; ++e) w[e] = W1[h * (D_ + E_) + D_ + e];
  DH[h] = 0.f; // v = 0 (PAD row is zero)
  for (int v = 1; v < V_; ++v) {
    float acc = 0.f;
#pragma unroll
    for (int e = 0; e < E_; ++e) acc += w[e] * table[v * E_ + e];
    DH[v * H_ + h] = acc;
  }
}

// ---------------- fp32 GEMM: Z[m][n] = sum_k A[m][k] * W1[n][k] + b1[n]
// A = inputs [65536 x 512] row-major, W1 rows are length D_+E_ (ldb = 576), Z [65536 x 512]
#define BM 128
#define BN 128
#define BK 16
#define LDS_S 132  // BM + 4 pad (keeps 16B alignment, breaks bank conflicts)

__global__ __launch_bounds__(256)
void gemm_kernel(const float* __restrict__ A, const float* __restrict__ W1,
                 const float* __restrict__ b1, float* __restrict__ Z) {
  __shared__ float As[BK * LDS_S];
  __shared__ float Bs[BK * LDS_S];
  const int t = threadIdx.x;
  const int mBase = blockIdx.x * BM;
  const int nBase = blockIdx.y * BN;
  const int tx = t & 15, ty = t >> 4;

  float acc[2][2][4][4];
#pragma unroll
  for (int a = 0; a < 2; a++)
#pragma unroll
    for (int b = 0; b < 2; b++)
#pragma unroll
      for (int i = 0; i < 4; i++)
#pragma unroll
        for (int j = 0; j < 4; j++) acc[a][b][i][j] = 0.f;

  const int rowA0 = t >> 2; // with idx = q*256 + t: row = q*64 + (t>>2), kq = t&3
  const int kq = t & 3;

  for (int kt = 0; kt < D_; kt += BK) {
#pragma unroll
    for (int q = 0; q < 2; ++q) {
      const int row = q * 64 + rowA0;
      const float4 av = *(const float4*)&A[(size_t)(mBase + row) * D_ + kt + kq * 4];
      const float4 bv = *(const float4*)&W1[(size_t)(nBase + row) * (D_ + E_) + kt + kq * 4];
#pragma unroll
      for (int i = 0; i < 4; ++i) As[(kq * 4 + i) * LDS_S + row] = ((const float*)&av)[i];
#pragma unroll
      for (int i = 0; i < 4; ++i) Bs[(kq * 4 + i) * LDS_S + row] = ((const float*)&bv)[i];
    }
    __syncthreads();
#pragma unroll
    for (int k = 0; k < BK; ++k) {
      float4 a0 = *(const float4*)&As[k * LDS_S + ty * 4];
      float4 a1 = *(const float4*)&As[k * LDS_S + ty * 4 + 64];
      float4 b0 = *(const float4*)&Bs[k * LDS_S + tx * 4];
      float4 b1v = *(const float4*)&Bs[k * LDS_S + tx * 4 + 64];
      float am[2][4] = {{a0.x, a0.y, a0.z, a0.w}, {a1.x, a1.y, a1.z, a1.w}};
      float bn[2][4] = {{b0.x, b0.y, b0.z, b0.w}, {b1v.x, b1v.y, b1v.z, b1v.w}};
#pragma unroll
      for (int am_ = 0; am_ < 2; am_++)
#pragma unroll
        for (int bn_ = 0; bn_ < 2; bn_++)
#pragma unroll
          for (int i = 0; i < 4; i++)
#pragma unroll
            for (int j = 0; j < 4; j++) acc[am_][bn_][i][j] += am[am_][i] * bn[bn_][j];
    }
    __syncthreads();
  }
#pragma unroll
  for (int bn_ = 0; bn_ < 2; ++bn_) {
    const int n0 = nBase + tx * 4 + bn_ * 64;
    const float4 bias = *(const float4*)&b1[n0];
#pragma unroll
    for (int am_ = 0; am_ < 2; ++am_) {
#pragma unroll
      for (int i = 0; i < 4; i++) {
        const int m = mBase + ty * 4 + am_ * 64 + i;
        float4 o;
        o.x = acc[am_][bn_][i][0] + bias.x;
        o.y = acc[am_][bn_][i][1] + bias.y;
        o.z = acc[am_][bn_][i][2] + bias.z;
        o.w = acc[am_][bn_][i][3] + bias.w;
        *(float4*)&Z[(size_t)m * H_ + n0] = o;
      }
    }
  }
}

// ---------------- sequential phase: 1 block per batch row, L-loop inside
#define SEQ_T 320

__global__ __launch_bounds__(SEQ_T)
void seq_kernel(const float* __restrict__ Z, const float* __restrict__ DH,
                const float* __restrict__ W2, const float* __restrict__ b2,
                const float* __restrict__ table,
                float* __restrict__ out_logits, float* __restrict__ out_preds,
                float* __restrict__ out_probs, float* __restrict__ out_pemb) {
  __shared__ float sDH[V_ * H_];   // 34 KB
  __shared__ float sH[16 * 36 + 32]; // h skewed: chunk s at s*36 (breaks 16-way conflict)
  __shared__ float sTab[V_ * E_];
  __shared__ float sLogit[32];
  __shared__ int sPred;

  const int b = blockIdx.x;
  const int j = threadIdx.x;

  for (int i = j; i < V_ * H_; i += SEQ_T) sDH[i] = DH[i];
  for (int i = j; i < V_ * E_; i += SEQ_T) sTab[i] = (i < E_) ? 0.f : table[i];

  // thread (v, s): v = j>>4 in [0,17), s = j&15; owns h-segment [s*32, s*32+32)
  float w2r[32];
  float b2r = 0.f;
  const int v = j >> 4, s = j & 15;
  if (j < 272) {
#pragma unroll
    for (int i = 0; i < 32; ++i) w2r[i] = W2[v * H_ + s * 32 + i];
    b2r = b2[v];
  }
  __syncthreads();

  int pred = 0;
  const float* Zb = Z + (size_t)b * L_ * H_;
  float z0 = 0.f, z1 = 0.f;
  if (j < 256) { z0 = Zb[j]; z1 = Zb[j + 256]; }

  for (int t = 0; t < L_; ++t) {
    if (j < 256) {
      const float h0 = tanhf(z0 + sDH[pred * H_ + j]);
      const float h1 = tanhf(z1 + sDH[pred * H_ + j + 256]);
      sH[j + 4 * (j >> 5)] = h0;
      const int j2 = j + 256;
      sH[j2 + 4 * (j2 >> 5)] = h1;
    }
    __syncthreads();
    if (j < 256 && t + 1 < L_) { // prefetch next Z row; latency hides under reduction
      z0 = Zb[(size_t)(t + 1) * H_ + j];
      z1 = Zb[(size_t)(t + 1) * H_ + j + 256];
    }
    if (j < 272) {
      const float* hc = &sH[s * 36];
      float p = 0.f;
#pragma unroll
      for (int i4 = 0; i4 < 8; ++i4) {
        const float4 hv = *(const float4*)&hc[i4 * 4];
        p += w2r[i4 * 4 + 0] * hv.x + w2r[i4 * 4 + 1] * hv.y +
             w2r[i4 * 4 + 2] * hv.z + w2r[i4 * 4 + 3] * hv.w;
      }
      p += __shfl_xor(p, 8, 16);
      p += __shfl_xor(p, 4, 16);
      p += __shfl_xor(p, 2, 16);
      p += __shfl_xor(p, 1, 16);
      if (s == 0) sLogit[v] = p + b2r;
    }
    __syncthreads();
    if (j < 64) {
      const float lv = (j < V_) ? sLogit[j] : -INFINITY;
      float m = lv;
#pragma unroll
      for (int o = 16; o >= 1; o >>= 1) m = fmaxf(m, __shfl_xor(m, o, 32));
      const float e = (j < V_) ? expf(lv - m) : 0.f;
      float ssum = e;
#pragma unroll
      for (int o = 16; o >= 1; o >>= 1) ssum += __shfl_xor(ssum, o, 32);
      const float lse = logf(ssum);
      int idx = (lv == m) ? j : 0x7fffffff; // first-max index, matches jnp.argmax
#pragma unroll
      for (int o = 16; o >= 1; o >>= 1) idx = min(idx, __shfl_xor(idx, o, 32));
      const size_t rowBT = (size_t)b * L_ + t;
      if (j < V_) {
        out_logits[rowBT * V_ + j] = lv;
        out_probs[rowBT * V_ + j] = lv - m - lse;
      }
      if (j == 0) {
        out_preds[rowBT] = (float)idx;
        sPred = idx;
      }
      if (j < 32) {
        out_pemb[rowBT * E_ + j] = sTab[idx * E_ + j];
        out_pemb[rowBT * E_ + j + 32] = sTab[idx * E_ + j + 32];
      }
    }
    __syncthreads();
    pred = sPred;
  }
}

extern "C" void kernel_launch(void* const* d_in, const int* in_sizes, int n_in,
                              void* d_out, int out_size, void* d_ws, size_t ws_size,
                              hipStream_t stream) {
  const float* inputs = (const float*)d_in[0];
  const float* table  = (const float*)d_in[1];
  const float* W1     = (const float*)d_in[2];
  const float* b1     = (const float*)d_in[3];
  const float* W2     = (const float*)d_in[4];
  const float* b2     = (const float*)d_in[5];

  float* out = (float*)d_out;
  float* out_logits = out;                                  // [B,L,V]
  float* out_preds  = out_logits + (size_t)B_ * L_ * V_;    // [B,L]
  float* out_probs  = out_preds + (size_t)B_ * L_;          // [B,L,V]
  float* out_pemb   = out_probs + (size_t)B_ * L_ * V_;     // [B,L,E]

  float* DH = (float*)d_ws;                                 // 17*512*4 = 34 KB
  float* Z  = (float*)((char*)d_ws + 65536);                // 65536*512*4 = 128 MB

  dh_kernel<<<1, 512, 0, stream>>>(W1, table, DH);
  dim3 g(65536 / BM, H_ / BN); // 512 x 4
  gemm_kernel<<<g, 256, 0, stream>>>(inputs, W1, b1, Z);
  seq_kernel<<<B_, SEQ_T, 0, stream>>>(Z, DH, W2, b2, table,
                                       out_logits, out_preds, out_probs, out_pemb);
}

// Round 2
// 1177.019 us; speedup vs baseline: 1.1512x; 1.1512x over previous
//
#include <hip/hip_runtime.h>
#include <math.h>

#define B_ 128
#define L_ 512
#define D_ 512
#define E_ 64
#define H_ 512
#define V_ 17

// ---------------- DH precompute: DH[v][h] = sum_e W1[h][D+e] * table[v][e], row 0 zeroed
__global__ void dh_kernel(const float* __restrict__ W1, const float* __restrict__ table,
                          float* __restrict__ DH) {
  int h = threadIdx.x; // 512 threads
  float w[E_];
#pragma unroll
  for (int e = 0; e < E_; ++e) w[e] = W1[h * (D_ + E_) + D_ + e];
  DH[h] = 0.f; // v = 0 (PAD row is zero)
  for (int v = 1; v < V_; ++v) {
    float acc = 0.f;
#pragma unroll
    for (int e = 0; e < E_; ++e) acc += w[e] * table[v * E_ + e];
    DH[v * H_ + h] = acc;
  }
}

// ---------------- fp32 GEMM: Z[m][n] = sum_k A[m][k] * W1[n][k] + b1[n]
#define BM 128
#define BN 128
#define BK 16
#define LDS_S 132

__global__ __launch_bounds__(256)
void gemm_kernel(const float* __restrict__ A, const float* __restrict__ W1,
                 const float* __restrict__ b1, float* __restrict__ Z) {
  __shared__ float As[BK * LDS_S];
  __shared__ float Bs[BK * LDS_S];
  const int t = threadIdx.x;
  const int mBase = blockIdx.x * BM;
  const int nBase = blockIdx.y * BN;
  const int tx = t & 15, ty = t >> 4;

  float acc[2][2][4][4];
#pragma unroll
  for (int a = 0; a < 2; a++)
#pragma unroll
    for (int b = 0; b < 2; b++)
#pragma unroll
      for (int i = 0; i < 4; i++)
#pragma unroll
        for (int j = 0; j < 4; j++) acc[a][b][i][j] = 0.f;

  const int rowA0 = t >> 2;
  const int kq = t & 3;

  for (int kt = 0; kt < D_; kt += BK) {
#pragma unroll
    for (int q = 0; q < 2; ++q) {
      const int row = q * 64 + rowA0;
      const float4 av = *(const float4*)&A[(size_t)(mBase + row) * D_ + kt + kq * 4];
      const float4 bv = *(const float4*)&W1[(size_t)(nBase + row) * (D_ + E_) + kt + kq * 4];
#pragma unroll
      for (int i = 0; i < 4; ++i) As[(kq * 4 + i) * LDS_S + row] = ((const float*)&av)[i];
#pragma unroll
      for (int i = 0; i < 4; ++i) Bs[(kq * 4 + i) * LDS_S + row] = ((const float*)&bv)[i];
    }
    __syncthreads();
#pragma unroll
    for (int k = 0; k < BK; ++k) {
      float4 a0 = *(const float4*)&As[k * LDS_S + ty * 4];
      float4 a1 = *(const float4*)&As[k * LDS_S + ty * 4 + 64];
      float4 b0 = *(const float4*)&Bs[k * LDS_S + tx * 4];
      float4 b1v = *(const float4*)&Bs[k * LDS_S + tx * 4 + 64];
      float am[2][4] = {{a0.x, a0.y, a0.z, a0.w}, {a1.x, a1.y, a1.z, a1.w}};
      float bn[2][4] = {{b0.x, b0.y, b0.z, b0.w}, {b1v.x, b1v.y, b1v.z, b1v.w}};
#pragma unroll
      for (int am_ = 0; am_ < 2; am_++)
#pragma unroll
        for (int bn_ = 0; bn_ < 2; bn_++)
#pragma unroll
          for (int i = 0; i < 4; i++)
#pragma unroll
            for (int j = 0; j < 4; j++) acc[am_][bn_][i][j] += am[am_][i] * bn[bn_][j];
    }
    __syncthreads();
  }
#pragma unroll
  for (int bn_ = 0; bn_ < 2; ++bn_) {
    const int n0 = nBase + tx * 4 + bn_ * 64;
    const float4 bias = *(const float4*)&b1[n0];
#pragma unroll
    for (int am_ = 0; am_ < 2; ++am_) {
#pragma unroll
      for (int i = 0; i < 4; i++) {
        const int m = mBase + ty * 4 + am_ * 64 + i;
        float4 o;
        o.x = acc[am_][bn_][i][0] + bias.x;
        o.y = acc[am_][bn_][i][1] + bias.y;
        o.z = acc[am_][bn_][i][2] + bias.z;
        o.w = acc[am_][bn_][i][3] + bias.w;
        *(float4*)&Z[(size_t)m * H_ + n0] = o;
      }
    }
  }
}

// ---------------- sequential phase: ONE WAVE per batch row. No s_barrier anywhere:
// intra-wave LDS ordering via compiler lgkmcnt; no vmcnt(0) drains, so the Z
// prefetch (2 steps ahead, ~1400cy cover vs ~900cy HBM latency) and the global
// stores stay in flight across steps.
#define LOG2E_F 1.4426950408889634f
#define LN2_F   0.6931471805599453f

__device__ __forceinline__ float fast_tanh(float x) {
  // tanh(x) = 1 - 2/(1+e^{2x}); saturates correctly via exp2 overflow/underflow
  float e = __builtin_amdgcn_exp2f(x * (2.0f * LOG2E_F));
  return 1.0f - 2.0f * __builtin_amdgcn_rcpf(e + 1.0f);
}

#define SP_PITCH 68  // 64 + 4 pad: reduce-read banks (4v+4i)%32 -> ~2-way (free)

__global__ __launch_bounds__(64, 1)
void seq_kernel(const float* __restrict__ Z, const float* __restrict__ DH,
                const float* __restrict__ W2, const float* __restrict__ b2,
                const float* __restrict__ table,
                float* __restrict__ out_logits, float* __restrict__ out_preds,
                float* __restrict__ out_probs, float* __restrict__ out_pemb) {
  __shared__ float sDH[V_ * H_];        // 34 KB
  __shared__ float sTab[V_ * E_];       // 4.25 KB
  __shared__ float sP[V_ * SP_PITCH];   // 4.5 KB partial-logit transpose

  const int b = blockIdx.x;
  const int ln = threadIdx.x; // 0..63

  // stage DH and (zero-padded) table into LDS
  for (int i = ln * 4; i < V_ * H_; i += 256)
    *(float4*)&sDH[i] = *(const float4*)&DH[i];
  for (int i = ln * 4; i < V_ * E_; i += 256) {
    float4 tv = *(const float4*)&table[i];
    if (i < E_) { tv.x = 0.f; tv.y = 0.f; tv.z = 0.f; tv.w = 0.f; } // PAD row
    *(float4*)&sTab[i] = tv;
  }

  // W2 fragments in registers: lane ln owns h-indices {4ln..4ln+3} u {256+4ln..}
  float w2a[V_][4], w2b[V_][4];
#pragma unroll
  for (int v = 0; v < V_; ++v) {
    *(float4*)w2a[v] = *(const float4*)&W2[v * H_ + 4 * ln];
    *(float4*)w2b[v] = *(const float4*)&W2[v * H_ + 256 + 4 * ln];
  }
  const float b2r = (ln < V_) ? b2[ln] : 0.f;

  const float* Zb = Z + (size_t)b * L_ * H_;
  // prefetch t=0 and t=1
  float4 za0 = *(const float4*)&Zb[4 * ln];
  float4 zb0 = *(const float4*)&Zb[256 + 4 * ln];
  float4 za1 = *(const float4*)&Zb[(size_t)H_ + 4 * ln];
  float4 zb1 = *(const float4*)&Zb[(size_t)H_ + 256 + 4 * ln];

  int pred = 0;

  auto step = [&](int t, float4& za, float4& zb) {
    // h = tanh(z + DH[pred])
    const float* dhrow = &sDH[pred * H_];
    const float4 da = *(const float4*)&dhrow[4 * ln];
    const float4 db = *(const float4*)&dhrow[256 + 4 * ln];
    float4 ha, hb;
    ha.x = fast_tanh(za.x + da.x); ha.y = fast_tanh(za.y + da.y);
    ha.z = fast_tanh(za.z + da.z); ha.w = fast_tanh(za.w + da.w);
    hb.x = fast_tanh(zb.x + db.x); hb.y = fast_tanh(zb.y + db.y);
    hb.z = fast_tanh(zb.z + db.z); hb.w = fast_tanh(zb.w + db.w);
    // prefetch t+2 into the regs just consumed (clamped tail load is harmless)
    {
      int tn = t + 2; if (tn > L_ - 1) tn = L_ - 1;
      za = *(const float4*)&Zb[(size_t)tn * H_ + 4 * ln];
      zb = *(const float4*)&Zb[(size_t)tn * H_ + 256 + 4 * ln];
    }
    // per-lane partial logits: 136 independent FMAs
    float p[V_];
#pragma unroll
    for (int v = 0; v < V_; ++v) {
      p[v] = w2a[v][0] * ha.x + w2a[v][1] * ha.y + w2a[v][2] * ha.z + w2a[v][3] * ha.w
           + w2b[v][0] * hb.x + w2b[v][1] * hb.y + w2b[v][2] * hb.z + w2b[v][3] * hb.w;
    }
#pragma unroll
    for (int v = 0; v < V_; ++v) sP[v * SP_PITCH + ln] = p[v];
    // lanes 0..16 each sum one row of 64 partials (intra-wave: lgkmcnt orders it)
    float lv = -INFINITY;
    if (ln < V_) {
      const float4* row = (const float4*)&sP[ln * SP_PITCH];
      float s0 = 0.f, s1 = 0.f, s2 = 0.f, s3 = 0.f;
#pragma unroll
      for (int i = 0; i < 16; ++i) {
        const float4 q = row[i];
        s0 += q.x; s1 += q.y; s2 += q.z; s3 += q.w;
      }
      lv = (s0 + s1) + (s2 + s3) + b2r;
    }
    // width-64 butterflies -> every lane gets max / sum / argmin-index
    float m = lv;
#pragma unroll
    for (int off = 32; off >= 1; off >>= 1) m = fmaxf(m, __shfl_xor(m, off, 64));
    const float e = __builtin_amdgcn_exp2f((lv - m) * LOG2E_F); // lv=-inf -> 0
    float ssum = e;
#pragma unroll
    for (int off = 32; off >= 1; off >>= 1) ssum += __shfl_xor(ssum, off, 64);
    const float lse = __builtin_amdgcn_logf(ssum) * LN2_F;
    int idx = (lv == m) ? ln : 0x7fffffff; // first-max, matches jnp.argmax
#pragma unroll
    for (int off = 32; off >= 1; off >>= 1) idx = min(idx, __shfl_xor(idx, off, 64));

    const size_t rowBT = (size_t)b * L_ + t;
    if (ln < V_) {
      out_logits[rowBT * V_ + ln] = lv;
      out_probs[rowBT * V_ + ln] = lv - m - lse;
    }
    if (ln == 0) out_preds[rowBT] = (float)idx;
    if (ln < 16) {
      const float4 ev = *(const float4*)&sTab[idx * E_ + 4 * ln];
      *(float4*)&out_pemb[rowBT * E_ + 4 * ln] = ev;
    }
    pred = idx; // uniform across the wave after the min-butterfly
  };

  for (int t = 0; t < L_; t += 2) {
    step(t, za0, zb0);
    step(t + 1, za1, zb1);
  }
}

extern "C" void kernel_launch(void* const* d_in, const int* in_sizes, int n_in,
                              void* d_out, int out_size, void* d_ws, size_t ws_size,
                              hipStream_t stream) {
  const float* inputs = (const float*)d_in[0];
  const float* table  = (const float*)d_in[1];
  const float* W1     = (const float*)d_in[2];
  const float* b1     = (const float*)d_in[3];
  const float* W2     = (const float*)d_in[4];
  const float* b2     = (const float*)d_in[5];

  float* out = (float*)d_out;
  float* out_logits = out;                                  // [B,L,V]
  float* out_preds  = out_logits + (size_t)B_ * L_ * V_;    // [B,L]
  float* out_probs  = out_preds + (size_t)B_ * L_;          // [B,L,V]
  float* out_pemb   = out_probs + (size_t)B_ * L_ * V_;     // [B,L,E]

  float* DH = (float*)d_ws;                                 // 34 KB
  float* Z  = (float*)((char*)d_ws + 65536);                // 128 MB

  dh_kernel<<<1, 512, 0, stream>>>(W1, table, DH);
  dim3 g(65536 / BM, H_ / BN); // 512 x 4
  gemm_kernel<<<g, 256, 0, stream>>>(inputs, W1, b1, Z);
  seq_kernel<<<B_, 64, 0, stream>>>(Z, DH, W2, b2, table,
                                    out_logits, out_preds, out_probs, out_pemb);
}